// Round 1
// baseline (212.103 us; speedup 1.0000x reference)
//
#include <hip/hip_runtime.h>
#include <math.h>

// KabschLoss: loss = mean( (xc @ R - yc)^2 ), R = U Vh from SVD of C = xc^T yc.
// Identity: sum |xc R - yc|^2 = Sx + Sy - 2*nuclear_norm(C)  (R orthogonal,
// tr(R^T C) = sum of singular values). So we only need per-batch raw moments
// and the singular values of the 3x3 covariance (closed-form eig of C^T C).

#define NPTS 128

__device__ __forceinline__ float xsum(float v, int m) {
    return v + __shfl_xor(v, m);
}

__global__ __launch_bounds__(256) void kabsch_kernel(
        const float* __restrict__ x, const float* __restrict__ y,
        float* __restrict__ out, float scale) {
    const int tid  = threadIdx.x;
    const int lane = tid & 63;
    const int wave = tid >> 6;
    const int g    = lane >> 3;   // group of 8 lanes -> one batch
    const int sub  = lane & 7;    // lane within group
    const int b    = blockIdx.x * 32 + wave * 8 + g;

    const float* xb = x + (size_t)b * (NPTS * 3);
    const float* yb = y + (size_t)b * (NPTS * 3);

    // 17 per-lane accumulators (raw moments)
    float sx0=0.f,sx1=0.f,sx2=0.f, sy0=0.f,sy1=0.f,sy2=0.f;
    float qx=0.f, qy=0.f;
    float c00=0.f,c01=0.f,c02=0.f,c10=0.f,c11=0.f,c12=0.f,c20=0.f,c21=0.f,c22=0.f;

    // Each lane handles 8 pairs of consecutive points: i0 = sub*2 + s*16.
    // 6 consecutive floats per array per step, 8-byte aligned -> 3x float2.
    #pragma unroll
    for (int s = 0; s < 8; ++s) {
        const int i0 = sub * 2 + s * 16;
        const float2* xp = (const float2*)(xb + i0 * 3);
        const float2* yp = (const float2*)(yb + i0 * 3);
        float2 xA = xp[0], xB = xp[1], xC = xp[2];
        float2 yA = yp[0], yB = yp[1], yC = yp[2];

        // point 0: (xA.x, xA.y, xB.x) ; point 1: (xB.y, xC.x, xC.y)
        {
            float px0=xA.x, px1=xA.y, px2=xB.x;
            float py0=yA.x, py1=yA.y, py2=yB.x;
            sx0+=px0; sx1+=px1; sx2+=px2;
            sy0+=py0; sy1+=py1; sy2+=py2;
            qx = fmaf(px0,px0,fmaf(px1,px1,fmaf(px2,px2,qx)));
            qy = fmaf(py0,py0,fmaf(py1,py1,fmaf(py2,py2,qy)));
            c00=fmaf(px0,py0,c00); c01=fmaf(px0,py1,c01); c02=fmaf(px0,py2,c02);
            c10=fmaf(px1,py0,c10); c11=fmaf(px1,py1,c11); c12=fmaf(px1,py2,c12);
            c20=fmaf(px2,py0,c20); c21=fmaf(px2,py1,c21); c22=fmaf(px2,py2,c22);
        }
        {
            float px0=xB.y, px1=xC.x, px2=xC.y;
            float py0=yB.y, py1=yC.x, py2=yC.y;
            sx0+=px0; sx1+=px1; sx2+=px2;
            sy0+=py0; sy1+=py1; sy2+=py2;
            qx = fmaf(px0,px0,fmaf(px1,px1,fmaf(px2,px2,qx)));
            qy = fmaf(py0,py0,fmaf(py1,py1,fmaf(py2,py2,qy)));
            c00=fmaf(px0,py0,c00); c01=fmaf(px0,py1,c01); c02=fmaf(px0,py2,c02);
            c10=fmaf(px1,py0,c10); c11=fmaf(px1,py1,c11); c12=fmaf(px1,py2,c12);
            c20=fmaf(px2,py0,c20); c21=fmaf(px2,py1,c21); c22=fmaf(px2,py2,c22);
        }
    }

    // Butterfly reduce the 17 sums within each 8-lane group (masks 1,2,4).
    #pragma unroll
    for (int m = 1; m <= 4; m <<= 1) {
        sx0=xsum(sx0,m); sx1=xsum(sx1,m); sx2=xsum(sx2,m);
        sy0=xsum(sy0,m); sy1=xsum(sy1,m); sy2=xsum(sy2,m);
        qx =xsum(qx ,m); qy =xsum(qy ,m);
        c00=xsum(c00,m); c01=xsum(c01,m); c02=xsum(c02,m);
        c10=xsum(c10,m); c11=xsum(c11,m); c12=xsum(c12,m);
        c20=xsum(c20,m); c21=xsum(c21,m); c22=xsum(c22,m);
    }
    // Now every lane in a group holds its batch's full sums.

    const float invN = 1.0f / (float)NPTS;
    // Mean-centered covariance C = Sxy - sx sy^T / N
    float C00 = c00 - sx0*sy0*invN, C01 = c01 - sx0*sy1*invN, C02 = c02 - sx0*sy2*invN;
    float C10 = c10 - sx1*sy0*invN, C11 = c11 - sx1*sy1*invN, C12 = c12 - sx1*sy2*invN;
    float C20 = c20 - sx2*sy0*invN, C21 = c21 - sx2*sy1*invN, C22 = c22 - sx2*sy2*invN;
    float Sx = qx - (sx0*sx0 + sx1*sx1 + sx2*sx2) * invN;
    float Sy = qy - (sy0*sy0 + sy1*sy1 + sy2*sy2) * invN;

    // A = C^T C (symmetric PSD); closed-form eigenvalues (trigonometric).
    float a00 = C00*C00 + C10*C10 + C20*C20;
    float a01 = C00*C01 + C10*C11 + C20*C21;
    float a02 = C00*C02 + C10*C12 + C20*C22;
    float a11 = C01*C01 + C11*C11 + C21*C21;
    float a12 = C01*C02 + C11*C12 + C21*C22;
    float a22 = C02*C02 + C12*C12 + C22*C22;

    float q = (a00 + a11 + a22) * (1.0f / 3.0f);
    float b00 = a00 - q, b11 = a11 - q, b22 = a22 - q;
    float p2 = (b00*b00 + b11*b11 + b22*b22
                + 2.0f * (a01*a01 + a02*a02 + a12*a12)) * (1.0f / 6.0f);
    float p = sqrtf(fmaxf(p2, 0.0f));
    float detB = b00 * (b11*b22 - a12*a12)
               - a01 * (a01*b22 - a12*a02)
               + a02 * (a01*a12 - b11*a02);
    float p3 = p * p * p;
    float r = (p3 > 1e-30f) ? (0.5f * detB / p3) : 0.0f;
    r = fminf(1.0f, fmaxf(-1.0f, r));
    float phi = acosf(r) * (1.0f / 3.0f);
    float two_p = 2.0f * p;
    float l1 = q + two_p * cosf(phi);                        // largest
    float l3 = q + two_p * cosf(phi + 2.0943951023931953f);  // smallest
    float l2 = 3.0f * q - l1 - l3;
    float nuc = sqrtf(fmaxf(l1, 0.0f)) + sqrtf(fmaxf(l2, 0.0f)) + sqrtf(fmaxf(l3, 0.0f));

    float term = Sx + Sy - 2.0f * nuc;

    // Sum the 8 distinct group terms across the wave (masks 8,16,32).
    term += __shfl_xor(term, 8);
    term += __shfl_xor(term, 16);
    term += __shfl_xor(term, 32);

    __shared__ float wsum[4];
    if (lane == 0) wsum[wave] = term;
    __syncthreads();
    if (tid == 0) {
        float t = (wsum[0] + wsum[1] + wsum[2] + wsum[3]) * scale;
        atomicAdd(out, t);
    }
}

extern "C" void kernel_launch(void* const* d_in, const int* in_sizes, int n_in,
                              void* d_out, int out_size, void* d_ws, size_t ws_size,
                              hipStream_t stream) {
    const float* x = (const float*)d_in[0];
    const float* y = (const float*)d_in[1];
    float* out = (float*)d_out;

    const int B = in_sizes[0] / (NPTS * 3);   // 65536
    const float scale = 1.0f / ((float)B * (float)NPTS * 3.0f);

    hipMemsetAsync(out, 0, sizeof(float), stream);   // harness poisons d_out
    const int blocks = B / 32;                       // 32 batches per 256-thread block
    kabsch_kernel<<<blocks, 256, 0, stream>>>(x, y, out, scale);
}